// Round 2
// baseline (19670.157 us; speedup 1.0000x reference)
//
#include <hip/hip_runtime.h>
#include <cstdint>

typedef __bf16 bf16;
typedef bf16 bf16x8 __attribute__((ext_vector_type(8)));
typedef bf16 bf16x4 __attribute__((ext_vector_type(4)));
typedef float f32x4 __attribute__((ext_vector_type(4)));

#define DI __device__ __forceinline__

DI float sigmoidf_(float x) { return 1.0f / (1.0f + __expf(-x)); }
DI float tanhf_(float x)    { return 1.0f - 2.0f / (__expf(2.0f * x) + 1.0f); }

// async global->LDS, 16B per lane; lds base must be wave-uniform (HW writes
// base + lane*16). Global address is per-lane (pre-swizzled source pattern).
DI void gld16(const void* g, void* l) {
  __builtin_amdgcn_global_load_lds(
      (const __attribute__((address_space(1))) void*)g,
      (__attribute__((address_space(3))) void*)l, 16, 0, 0);
}

// ---------------------------------------------------------------------------
// LDS chunk layout: [rows][64 k] bf16 = 128 B/row, slot s (16B) holds
// act[r][k0 + (s ^ (r&7))*8]  (XOR swizzle -> bank-balanced ds_read_b128).
// ---------------------------------------------------------------------------
template<int SE>   // stage 128 rows x 64k from one act (row stride SE elems)
DI void stage128(char* ldsb, const bf16* act, int k0, int wave, int lane)
{
  const int rsub = lane >> 3, s = lane & 7;
#pragma unroll
  for (int j = 0; j < 4; ++j) {
    const int r = (wave * 4 + j) * 8 + rsub;
    gld16(act + (long)r * SE + k0 + ((s ^ (r & 7)) << 3),
          ldsb + (wave * 4 + j) * 1024);
  }
}

template<int SE>   // stage 64 rows x 64k from each of two acts (dual GEMM)
DI void stage64x2(char* ldsb, const bf16* a1, const bf16* a2, int k0,
                  int wave, int lane)
{
  const int rsub = lane >> 3, s = lane & 7;
#pragma unroll
  for (int j = 0; j < 2; ++j) {
    const int r = (wave * 2 + j) * 8 + rsub;
    const long go = (long)r * SE + k0 + ((s ^ (r & 7)) << 3);
    gld16(a1 + go, ldsb + (wave * 2 + j) * 1024);
    gld16(a2 + go, ldsb + 8192 + (wave * 2 + j) * 1024);
  }
}

DI bf16x8 ldsAf(const char* p, int r, int m)   // m = k-slot index (pre-XOR)
{
  return *(const bf16x8*)(p + r * 128 + ((m ^ (r & 7)) << 4));
}

// ---------------------------------------------------------------------------
// Legacy direct-from-global GEMM core (kept for the small split-K single_li).
// ---------------------------------------------------------------------------
template<int NB, int K, int STRIDE>
DI void mmK(f32x4* acc, const bf16* __restrict__ wrow,
            const bf16* __restrict__ act, int q, int col)
{
#pragma unroll
  for (int ki = 0; ki < K / 32; ++ki) {
    const int k = ki * 32 + q * 8;
    bf16x8 wf = *(const bf16x8*)(wrow + k);
#pragma unroll
    for (int bt = 0; bt < NB; ++bt) {
      bf16x8 af = *(const bf16x8*)(act + (long)(bt * 16 + col) * STRIDE + k);
      acc[bt] = __builtin_amdgcn_mfma_f32_16x16x32_bf16(wf, af, acc[bt], 0, 0, 0);
    }
  }
}

// --------------------------- LSTM level (device part) ----------------------
// task in [0,96): bx=ntile64(32) x axis(3). Full batch per wave (NB=8).
DI void d_lstm(int bid, int tid, char* smem,
               const bf16* __restrict__ A0, long a0ss,
               const bf16* __restrict__ A1,
               const bf16* __restrict__ W,
               const float* __restrict__ bias,
               const float* __restrict__ csR,
               float* __restrict__ csW,
               bf16* __restrict__ hOut)
{
  const int bx = bid & 31, ax = bid >> 5;
  const int lane = tid & 63, wave = tid >> 6;
  const int q = lane >> 4, col = lane & 15;
  const int n0 = bx * 64 + wave * 16;
  const bf16* wrow = W + (long)ax * 10485760L + (long)(n0 + col) * 1024;
  const bf16* a0 = A0 + (long)ax * a0ss;
  const bf16* a1 = A1 + (long)ax * 65536;
  f32x4 acc[8] = {};
  stage128<512>(smem, a0, 0, wave, lane);
  __syncthreads();
#pragma unroll 2
  for (int c = 0; c < 16; ++c) {
    if (c < 15) {
      const bf16* an = ((c + 1) < 8) ? a0 : a1;
      stage128<512>(smem + (((c + 1) & 1) << 14), an, ((c + 1) & 7) * 64,
                    wave, lane);
    }
    const char* p = smem + ((c & 1) << 14);
#pragma unroll
    for (int ki = 0; ki < 2; ++ki) {
      bf16x8 wf = *(const bf16x8*)(wrow + c * 64 + ki * 32 + q * 8);
#pragma unroll
      for (int bt = 0; bt < 8; ++bt)
        acc[bt] = __builtin_amdgcn_mfma_f32_16x16x32_bf16(
            wf, ldsAf(p, bt * 16 + col, ki * 4 + q), acc[bt], 0, 0, 0);
    }
    __syncthreads();
  }
  const int o = (n0 >> 2) + q;
  const float* bi = bias + (long)ax * 10240;
  float b0f = bi[o], b1f = bi[512 + o], b2f = bi[1024 + o], b3f = bi[1536 + o];
  const float* csr = csR + (long)ax * 65536;
  float* csw = csW + (long)ax * 65536;
  bf16* hl = hOut + (long)ax * 65536;
#pragma unroll
  for (int bt = 0; bt < 8; ++bt) {
    int b = bt * 16 + col;
    float ig = sigmoidf_(acc[bt][0] + b0f);
    float fg = sigmoidf_(acc[bt][1] + b1f);
    float gg = tanhf_   (acc[bt][2] + b2f);
    float og = sigmoidf_(acc[bt][3] + b3f);
    long idx = (long)b * 512 + o;
    float cn = fg * csr[idx] + ig * gg;
    csw[idx] = cn;
    hl[idx] = (bf16)(og * tanhf_(cn));
  }
}

// --------------------------- cell_fn gates (device part) -------------------
// task in [0,480): bx=ntile64(32) x sl=l*3+a(15). Full batch per wave (NB=8).
DI void d_cell(int bid, int tid, char* smem,
               const bf16* __restrict__ hg, const bf16* __restrict__ hsC,
               const bf16* __restrict__ Wg, const float* __restrict__ bgp,
               const float* __restrict__ csC,
               bf16* __restrict__ icat, bf16* __restrict__ ccat)
{
  const int bx = bid & 31, sl = bid >> 5;
  const int l = sl / 3, a = sl - l * 3;
  const int lane = tid & 63, wave = tid >> 6;
  const int q = lane >> 4, col = lane & 15;
  const int n0 = bx * 64 + wave * 16;
  const bf16* wrow = Wg + (long)sl * 2097152L + (long)(n0 + col) * 1024;
  const bf16* a0 = hg;
  const bf16* a1 = hsC + (long)sl * 65536;
  f32x4 acc[8] = {};
  stage128<512>(smem, a0, 0, wave, lane);
  __syncthreads();
#pragma unroll 2
  for (int c = 0; c < 16; ++c) {
    if (c < 15) {
      const bf16* an = ((c + 1) < 8) ? a0 : a1;
      stage128<512>(smem + (((c + 1) & 1) << 14), an, ((c + 1) & 7) * 64,
                    wave, lane);
    }
    const char* p = smem + ((c & 1) << 14);
#pragma unroll
    for (int ki = 0; ki < 2; ++ki) {
      bf16x8 wf = *(const bf16x8*)(wrow + c * 64 + ki * 32 + q * 8);
#pragma unroll
      for (int bt = 0; bt < 8; ++bt)
        acc[bt] = __builtin_amdgcn_mfma_f32_16x16x32_bf16(
            wf, ldsAf(p, bt * 16 + col, ki * 4 + q), acc[bt], 0, 0, 0);
    }
    __syncthreads();
  }
  const int z = (n0 >> 2) + q;
  const float* bgl = bgp + (long)sl * 1536;
  float g0 = bgl[z], g1 = bgl[512 + z], g2 = bgl[1024 + z];
  const float* csl = csC + (long)sl * 65536;
  const long obase = (long)l * 196608 + (long)a * 512 + z;
#pragma unroll
  for (int bt = 0; bt < 8; ++bt) {
    int b = bt * 16 + col;
    float ig = sigmoidf_(acc[bt][0] + g0);
    float fg = sigmoidf_(acc[bt][1] + g1);
    float gg = tanhf_   (acc[bt][2] + g2);
    float sc = csl[(long)b * 512 + z];
    float icl = ig * sc;
    float ccl = fg * gg + icl;
    long oi = obase + (long)b * 1536;
    icat[oi] = (bf16)icl;
    ccat[oi] = (bf16)ccl;
  }
}

// ----------------------- t1/t2 dual GEMM (device part) ---------------------
// task in [0,80): bx=ntile64(8) x by=batch-half(2) x l(5). NB=4 dual.
DI void d_tg(int bid, int tid, char* smem,
             const bf16* __restrict__ icat, const bf16* __restrict__ ccat,
             const bf16* __restrict__ Wt, const float* __restrict__ bilc,
             float* __restrict__ t1s, float* __restrict__ t2s)
{
  const int bx = bid & 7, by = (bid >> 3) & 1, l = bid >> 4;
  const int lane = tid & 63, wave = tid >> 6;
  const int q = lane >> 4, col = lane & 15;
  const int n0 = bx * 64 + wave * 16;
  const int b0 = by * 64;
  const bf16* wrow = Wt + (long)l * 786432L + (long)(n0 + col) * 1536;
  const bf16* ic = icat + (long)l * 196608 + (long)b0 * 1536;
  const bf16* cc = ccat + (long)l * 196608 + (long)b0 * 1536;
  f32x4 a1[4] = {}, a2[4] = {};
  stage64x2<1536>(smem, ic, cc, 0, wave, lane);
  __syncthreads();
#pragma unroll 2
  for (int c = 0; c < 24; ++c) {
    if (c < 23)
      stage64x2<1536>(smem + (((c + 1) & 1) << 14), ic, cc, (c + 1) * 64,
                      wave, lane);
    const char* p = smem + ((c & 1) << 14);
#pragma unroll
    for (int ki = 0; ki < 2; ++ki) {
      bf16x8 wf = *(const bf16x8*)(wrow + c * 64 + ki * 32 + q * 8);
#pragma unroll
      for (int bt = 0; bt < 4; ++bt) {
        int rl = bt * 16 + col;
        a1[bt] = __builtin_amdgcn_mfma_f32_16x16x32_bf16(
            wf, ldsAf(p, rl, ki * 4 + q), a1[bt], 0, 0, 0);
        a2[bt] = __builtin_amdgcn_mfma_f32_16x16x32_bf16(
            wf, ldsAf(p + 8192, rl, ki * 4 + q), a2[bt], 0, 0, 0);
      }
    }
    __syncthreads();
  }
  const int yb = n0 + 4 * q;
  const float* bl = bilc + (long)l * 1536;
  f32x4 bs;
#pragma unroll
  for (int r = 0; r < 4; ++r) bs[r] = bl[yb + r] + bl[512 + yb + r] + bl[1024 + yb + r];
#pragma unroll
  for (int bt = 0; bt < 4; ++bt) {
    int b = b0 + bt * 16 + col;
    f32x4 v1 = a1[bt] + bs, v2 = a2[bt] + bs;
    *(f32x4*)(t1s + ((long)l * 128 + b) * 512 + yb) = v1;
    *(f32x4*)(t2s + ((long)l * 128 + b) * 512 + yb) = v2;
  }
}

// ------------------ softmax/sigmoid combine (device part) ------------------
// task in [0,160): bx=b-tile-of-4(32) x l(5); one (l,b)-row of 512 per wave.
DI void d_comb(int bid, int tid,
               const float* __restrict__ t1s, const float* __restrict__ t2s,
               bf16* __restrict__ cat)
{
  const int bx = bid & 31, l = bid >> 5;
  const int lane = tid & 63, wave = tid >> 6;
  const int b = bx * 4 + wave;
  const float* r1 = t1s + ((long)l * 128 + b) * 512 + lane * 8;
  const float* r2 = t2s + ((long)l * 128 + b) * 512 + lane * 8;
  f32x4 u0 = *(const f32x4*)r1, u1 = *(const f32x4*)(r1 + 4);
  float mx = u0[0];
#pragma unroll
  for (int j = 1; j < 4; ++j) mx = fmaxf(mx, u0[j]);
#pragma unroll
  for (int j = 0; j < 4; ++j) mx = fmaxf(mx, u1[j]);
  for (int d = 32; d > 0; d >>= 1) mx = fmaxf(mx, __shfl_xor(mx, d, 64));
  float e[8], ss = 0.f;
#pragma unroll
  for (int j = 0; j < 4; ++j) { e[j] = __expf(u0[j] - mx); ss += e[j]; }
#pragma unroll
  for (int j = 0; j < 4; ++j) { e[4 + j] = __expf(u1[j] - mx); ss += e[4 + j]; }
  for (int d = 32; d > 0; d >>= 1) ss += __shfl_xor(ss, d, 64);
  float inv = 1.0f / ss;
  f32x4 w0 = *(const f32x4*)r2, w1 = *(const f32x4*)(r2 + 4);
  bf16x8 ob;
#pragma unroll
  for (int j = 0; j < 4; ++j) ob[j]     = (bf16)(sigmoidf_(w0[j]) * e[j]     * inv);
#pragma unroll
  for (int j = 0; j < 4; ++j) ob[4 + j] = (bf16)(sigmoidf_(w1[j]) * e[4 + j] * inv);
  *(bf16x8*)(cat + (long)b * 2560 + l * 512 + lane * 8) = ob;
}

// ---------------- single_li split-K GEMM (device part) ---------------------
// task in [0,128): bx=ntile64(8) x by=batch-quarter(4) x kc(4). NB=2, K=640.
DI void d_slg(int bid, int tid,
              const bf16* __restrict__ cat, const bf16* __restrict__ Wsl,
              float* __restrict__ hnewp)
{
  const int bx = bid & 7, by = (bid >> 3) & 3, kc = bid >> 5;
  const int lane = tid & 63, wave = tid >> 6;
  const int q = lane >> 4, col = lane & 15;
  const int n0 = bx * 64 + wave * 16;
  const int b0 = by * 32;
  const bf16* wrow = Wsl + (long)(n0 + col) * 2560 + kc * 640;
  const bf16* act = cat + kc * 640 + (long)b0 * 2560;
  f32x4 acc[2] = {};
  mmK<2, 640, 2560>(acc, wrow, act, q, col);
  const int nb = n0 + 4 * q;
#pragma unroll
  for (int bt = 0; bt < 2; ++bt) {
    int b = b0 + bt * 16 + col;
    *(f32x4*)(hnewp + ((long)kc * 128 + b) * 512 + nb) = acc[bt];
  }
}

// -------- finalize: sum K-partials, +bsl, write h_g (bf16) and y ----------
// task in [0,32): one wave per batch row b.
DI void d_fin(int bid, int tid,
              const float* __restrict__ hnewp, const float* __restrict__ bsl,
              const float* __restrict__ wlin, const float* __restrict__ blin,
              bf16* __restrict__ hg, float* __restrict__ out, int t)
{
  const int lane = tid & 63, wave = tid >> 6;
  const int b = bid * 4 + wave;
  const int h0 = lane * 8;
  f32x4 s0 = {0,0,0,0}, s1 = {0,0,0,0};
#pragma unroll
  for (int kc = 0; kc < 4; ++kc) {
    const float* p = hnewp + ((long)kc * 128 + b) * 512 + h0;
    s0 += *(const f32x4*)p;
    s1 += *(const f32x4*)(p + 4);
  }
  s0 += *(const f32x4*)(bsl + h0);
  s1 += *(const f32x4*)(bsl + h0 + 4);
  bf16x8 hb;
#pragma unroll
  for (int j = 0; j < 4; ++j) { hb[j] = (bf16)s0[j]; hb[4 + j] = (bf16)s1[j]; }
  *(bf16x8*)(hg + (long)b * 512 + h0) = hb;
  const float* wl = wlin + (long)t * 512 + h0;
  f32x4 w0 = *(const f32x4*)wl, w1 = *(const f32x4*)(wl + 4);
  float dot = s0[0]*w0[0] + s0[1]*w0[1] + s0[2]*w0[2] + s0[3]*w0[3]
            + s1[0]*w1[0] + s1[1]*w1[1] + s1[2]*w1[2] + s1[3]*w1[3];
  for (int d = 32; d > 0; d >>= 1) dot += __shfl_xor(dot, d, 64);
  if (lane == 0) out[t * 128 + b] = dot + blin[t];
}

// ------------------------- grid barrier (persistent) -----------------------
// Two-level arrive (8 groups x 64 blocks -> root -> gen), monotonic gen.
// All counters monotonic: no reset races. thread0 arrives/polls; block parks
// at __syncthreads. __threadfence on both sides = device-scope release/acquire
// (L2 writeback / L1+L2 invalidate) so cross-XCD data is coherent.
DI void gsync(unsigned* bar, int bid, unsigned target)
{
  __syncthreads();
  if (threadIdx.x == 0) {
    __threadfence();   // release: flush this block's writes to coherent point
    unsigned o = __hip_atomic_fetch_add(&bar[(bid & 7) * 32], 1u,
                     __ATOMIC_ACQ_REL, __HIP_MEMORY_SCOPE_AGENT);
    if ((o & 63u) == 63u) {            // 64th arrival of this group's round
      unsigned r = __hip_atomic_fetch_add(&bar[256], 1u,
                       __ATOMIC_ACQ_REL, __HIP_MEMORY_SCOPE_AGENT);
      if ((r & 7u) == 7u)              // 8th group of this round
        __hip_atomic_fetch_add(&bar[288], 1u,
            __ATOMIC_ACQ_REL, __HIP_MEMORY_SCOPE_AGENT);
    }
    while (__hip_atomic_load(&bar[288], __ATOMIC_RELAXED,
                             __HIP_MEMORY_SCOPE_AGENT) < target)
      __builtin_amdgcn_s_sleep(2);
    __threadfence();   // acquire: invalidate L1/L2 before reading others' data
  }
  __syncthreads();
}

// ---------------------- persistent full-sequence kernel --------------------
struct KArgs {
  const bf16 *xbf, *Wcat, *Wg, *Wt, *Wslb;
  const float *b_l, *bg, *bilc, *bsl, *Wlin, *blin;
  bf16 *hs0, *hs1, *hgb, *icat, *ccat, *catb;
  float *cs0, *cs1, *t1s, *t2s, *hnp, *out;
  unsigned *bar;
};

// Grid = 512 blocks x 256 threads = exactly 2 blocks/CU on 256 CUs.
// launch_bounds(256,2) caps VGPR<=256; LDS 32KB/block -> 64KB/CU. Both within
// 2-block capacity => all 512 blocks co-resident (no cooperative API needed).
__global__ __launch_bounds__(256, 2) void k_main(KArgs A)
{
  __shared__ __align__(16) char smem[32768];
  const int bid = blockIdx.x;
  const int tid = threadIdx.x;
  unsigned round = 0;

  for (int s = 0; s < 65; ++s) {
    const int t  = (s < 64) ? s : 63;     // lstm step (active iff s<64)
    const int tc = s - 1;                 // chain step (active iff s>0)
    const int ln = (s < 64) ? 96 : 0;
    const bf16*  hsR = (t & 1) ? A.hs1 : A.hs0;
    bf16*        hsW = (t & 1) ? A.hs0 : A.hs1;
    const float* csR = (t & 1) ? A.cs1 : A.cs0;
    float*       csW = (t & 1) ? A.cs0 : A.cs1;
    const bf16*  hsC = (tc & 1) ? A.hs0 : A.hs1;   // = hsW(tc)
    const float* csC = (tc & 1) ? A.cs0 : A.cs1;   // = csW(tc)

#define LSTM_L(l, task) d_lstm(task, tid, smem, \
      ((l) == 0 ? A.xbf + (long)t * 65536 : (const bf16*)(hsW + (long)((l)-1) * 196608)), \
      ((l) == 0 ? 0L : 65536L), \
      hsR + (long)(l) * 196608, A.Wcat + (long)(l) * 2097152, \
      A.b_l + (long)(l) * 2048, csR + (long)(l) * 196608, \
      csW + (long)(l) * 196608, hsW + (long)(l) * 196608)

    // ---- phase 0: lstm level0 (96) + cell gates (480) = up to 576 tasks ---
    {
      const int tot = ln + ((s > 0) ? 480 : 0);
      if (bid < tot) {
        if (bid < ln) LSTM_L(0, bid);
        else d_cell(bid - ln, tid, smem, A.hgb, hsC, A.Wg, A.bg, csC,
                    A.icat, A.ccat);
      }
      const int t2 = 1023 - bid;          // blocks 448..511 take tasks 512..575
      if (t2 >= 512 && t2 < tot)
        d_cell(t2 - ln, tid, smem, A.hgb, hsC, A.Wg, A.bg, csC,
               A.icat, A.ccat);
      gsync(A.bar, bid, ++round);
    }
    // ---- phase 1: lstm level1 (96) + t1/t2 dual GEMM (80) -----------------
    {
      const int tot = ln + ((s > 0) ? 80 : 0);
      if (bid < tot) {
        if (bid < ln) LSTM_L(1, bid);
        else d_tg(bid - ln, tid, smem, A.icat, A.ccat, A.Wt, A.bilc,
                  A.t1s, A.t2s);
      }
      gsync(A.bar, bid, ++round);
    }
    // ---- phase 2: lstm level2 (96) + combine (160) ------------------------
    {
      const int tot = ln + ((s > 0) ? 160 : 0);
      if (bid < tot) {
        if (bid < ln) LSTM_L(2, bid);
        else d_comb(bid - ln, tid, A.t1s, A.t2s, A.catb);
      }
      gsync(A.bar, bid, ++round);
    }
    // ---- phase 3: lstm level3 (96) + single_li split-K (128) --------------
    {
      const int tot = ln + ((s > 0) ? 128 : 0);
      if (bid < tot) {
        if (bid < ln) LSTM_L(3, bid);
        else d_slg(bid - ln, tid, A.catb, A.Wslb, A.hnp);
      }
      gsync(A.bar, bid, ++round);
    }
    // ---- phase 4: lstm level4 (96) + finalize (32) ------------------------
    {
      const int tot = ln + ((s > 0) ? 32 : 0);
      if (bid < tot) {
        if (bid < ln) LSTM_L(4, bid);
        else d_fin(bid - ln, tid, A.hnp, A.bsl, A.Wlin, A.blin, A.hgb,
                   A.out, tc);
      }
      gsync(A.bar, bid, ++round);
    }
#undef LSTM_L
  }
}

// ------------------------- weight conversion kernels -----------------------
__global__ __launch_bounds__(256) void cvt_wxh(const float* __restrict__ Wx,
    const float* __restrict__ Wh, bf16* __restrict__ dst)
{
  long idx = ((long)blockIdx.x * 256 + threadIdx.x) * 4;   // [al][n][k], n=4o+g
  int k = (int)(idx & 1023);
  int n = (int)((idx >> 10) & 2047);
  long al = idx >> 21;                                     // a*5+l
  int g = n & 3, o = n >> 2;
  const float* src = (k < 512)
      ? Wx + ((al * 4 + g) * 512 + o) * 512 + k
      : Wh + ((al * 4 + g) * 512 + o) * 512 + (k - 512);
  f32x4 v = *(const f32x4*)src;
  bf16x4 ov;
#pragma unroll
  for (int j = 0; j < 4; ++j) ov[j] = (bf16)v[j];
  *(bf16x4*)(dst + idx) = ov;
}

__global__ __launch_bounds__(256) void cvt_wg(const float* __restrict__ Wg_h,
    const float* __restrict__ Wg_p, bf16* __restrict__ dst)
{
  long idx = ((long)blockIdx.x * 256 + threadIdx.x) * 4;   // [la][n=4z+g][k], g==3 pad
  int k = (int)(idx & 1023);
  int n = (int)((idx >> 10) & 2047);
  long la = idx >> 21;                                     // l*3+a
  int g = n & 3, z = n >> 2;
  f32x4 v = {0, 0, 0, 0};
  if (g < 3) {
    const float* src = (k < 512)
        ? Wg_h + ((la * 3 + g) * 512 + z) * 512 + k
        : Wg_p + ((la * 3 + g) * 512 + z) * 512 + (k - 512);
    v = *(const f32x4*)src;
  }
  bf16x4 ov;
#pragma unroll
  for (int j = 0; j < 4; ++j) ov[j] = (bf16)v[j];
  *(bf16x4*)(dst + idx) = ov;
}

__global__ __launch_bounds__(256) void cvt_wt(const float* __restrict__ Wilc,
                                              bf16* __restrict__ dst)
{
  long idx = (long)blockIdx.x * 256 + threadIdx.x;         // [l][y][k=a*512+z]
  int k = (int)(idx % 1536);
  long rest = idx / 1536;
  int y = (int)(rest & 511);
  int l = (int)(rest >> 9);
  int a = k >> 9, z = k & 511;
  dst[idx] = (bf16)Wilc[(((long)l * 3 + a) * 512 + z) * 512 + y];
}

__global__ __launch_bounds__(256) void k_cast(const float* __restrict__ s,
                                              bf16* __restrict__ d)
{
  long i = ((long)blockIdx.x * 256 + threadIdx.x) * 4;
  f32x4 v = *(const f32x4*)(s + i);
  bf16x4 ov;
#pragma unroll
  for (int j = 0; j < 4; ++j) ov[j] = (bf16)v[j];
  *(bf16x4*)(d + i) = ov;
}

__global__ __launch_bounds__(256) void k_zero(uint4* __restrict__ p, long n)
{
  long i = (long)blockIdx.x * 256 + threadIdx.x;
  if (i < n) p[i] = make_uint4(0, 0, 0, 0);
}

// ---------------------------------------------------------------------------
extern "C" void kernel_launch(void* const* d_in, const int* in_sizes, int n_in,
                              void* d_out, int out_size, void* d_ws, size_t ws_size,
                              hipStream_t stream)
{
  const float* x    = (const float*)d_in[0];
  const float* Wx   = (const float*)d_in[1];
  const float* Wh   = (const float*)d_in[2];
  const float* b_l  = (const float*)d_in[3];
  const float* Wg_h = (const float*)d_in[4];
  const float* Wg_p = (const float*)d_in[5];
  const float* bg   = (const float*)d_in[6];
  const float* Wilc = (const float*)d_in[7];
  const float* bilc = (const float*)d_in[8];
  const float* Wsl  = (const float*)d_in[9];
  const float* bsl  = (const float*)d_in[10];
  const float* Wlin = (const float*)d_in[11];
  const float* blin = (const float*)d_in[12];
  float* out = (float*)d_out;

  char* w = (char*)d_ws;
  auto alloc = [&](long bytes) { char* p = w; w += (bytes + 255) & ~255L; return p; };
  bf16* Wcat = (bf16*)alloc(31457280L * 2);   // [a][l][2048][1024]
  bf16* Wg   = (bf16*)alloc(31457280L * 2);   // [l*3+a][2048][1024]
  bf16* Wt   = (bf16*)alloc(3932160L * 2);    // [l][512][1536]
  bf16* Wslb = (bf16*)alloc(1310720L * 2);    // [512][2560]
  bf16* xbf  = (bf16*)alloc(4194304L * 2);    // [t][b][512]
  char* zbase = w;
  bf16* hs0  = (bf16*)alloc(983040L * 2);     // [l][a][b][512] ping
  bf16* hs1  = (bf16*)alloc(983040L * 2);     // pong
  bf16* hgb  = (bf16*)alloc(65536L * 2);      // [b][512]
  float* cs0 = (float*)alloc(983040L * 4);    // [l][a][b][512] ping
  float* cs1 = (float*)alloc(983040L * 4);    // pong
  unsigned* bar = (unsigned*)alloc(1536);     // grid barrier counters
  long zbytes = w - zbase;
  bf16* icat = (bf16*)alloc(983040L * 2);     // [l][b][1536]
  bf16* ccat = (bf16*)alloc(983040L * 2);
  float* t1s = (float*)alloc(327680L * 4);    // [l][b][512]
  float* t2s = (float*)alloc(327680L * 4);
  bf16* catb = (bf16*)alloc(327680L * 2);     // [b][2560]
  float* hnp = (float*)alloc(262144L * 4);    // [kc][b][512]
  (void)ws_size; (void)n_in; (void)in_sizes; (void)out_size;

  // --- setup (runs every call; ws is re-poisoned by the harness) ---
  cvt_wxh<<<30720, 256, 0, stream>>>(Wx, Wh, Wcat);
  cvt_wg <<<30720, 256, 0, stream>>>(Wg_h, Wg_p, Wg);
  cvt_wt <<<15360, 256, 0, stream>>>(Wilc, Wt);
  k_cast <<<1280,  256, 0, stream>>>(Wsl, Wslb);
  k_cast <<<4096,  256, 0, stream>>>(x, xbf);
  {
    long n16 = zbytes / 16;
    k_zero<<<(int)((n16 + 255) / 256), 256, 0, stream>>>((uint4*)zbase, n16);
  }

  // --- single persistent kernel runs the whole pipelined sequence ----------
  KArgs A;
  A.xbf = xbf; A.Wcat = Wcat; A.Wg = Wg; A.Wt = Wt; A.Wslb = Wslb;
  A.b_l = b_l; A.bg = bg; A.bilc = bilc; A.bsl = bsl; A.Wlin = Wlin; A.blin = blin;
  A.hs0 = hs0; A.hs1 = hs1; A.hgb = hgb; A.icat = icat; A.ccat = ccat; A.catb = catb;
  A.cs0 = cs0; A.cs1 = cs1; A.t1s = t1s; A.t2s = t2s; A.hnp = hnp; A.out = out;
  A.bar = bar;
  k_main<<<512, 256, 0, stream>>>(A);
}

// Round 5
// 14480.280 us; speedup vs baseline: 1.3584x; 1.3584x over previous
//
#include <hip/hip_runtime.h>
#include <cstdint>

typedef __bf16 bf16;
typedef unsigned long long u64;
typedef bf16 bf16x8 __attribute__((ext_vector_type(8)));
typedef bf16 bf16x4 __attribute__((ext_vector_type(4)));
typedef float f32x4 __attribute__((ext_vector_type(4)));
typedef u64 u64x2 __attribute__((ext_vector_type(2)));

#define DI __device__ __forceinline__

DI float sigmoidf_(float x) { return 1.0f / (1.0f + __expf(-x)); }
DI float tanhf_(float x)    { return 1.0f - 2.0f / (__expf(2.0f * x) + 1.0f); }

// ---------------------------------------------------------------------------
// Agent-coherent scalar accessors. RELAXED+AGENT atomics compile to plain
// loads/stores with per-access coherence bits (bypass stale L1/local-L2) —
// NO cache-wide writeback/invalidate. Round-2's __threadfence acquire-side
// invalidate flushed clean weight lines from every XCD L2 each barrier
// (136 MB refetch/iter at 460 GB/s = the 2.5x regression). Weights stay
// normally cached; only small cross-block activations pay the coherent path.
// ---------------------------------------------------------------------------
DI u64 cload_u64(const void* p) {
  return __hip_atomic_load((const u64*)p, __ATOMIC_RELAXED,
                           __HIP_MEMORY_SCOPE_AGENT);
}
DI void cstore_u64(void* p, u64 v) {
  __hip_atomic_store((u64*)p, v, __ATOMIC_RELAXED, __HIP_MEMORY_SCOPE_AGENT);
}
DI float cload_f32(const float* p) {
  unsigned u = __hip_atomic_load((const unsigned*)p, __ATOMIC_RELAXED,
                                 __HIP_MEMORY_SCOPE_AGENT);
  union { unsigned u; float f; } x; x.u = u; return x.f;
}
DI void cstore_f32(float* p, float v) {
  union { float f; unsigned u; } x; x.f = v;
  __hip_atomic_store((unsigned*)p, x.u, __ATOMIC_RELAXED,
                     __HIP_MEMORY_SCOPE_AGENT);
}
DI void cstore_bf16(bf16* p, bf16 v) {
  union { bf16 b; unsigned short u; } x; x.b = v;
  __hip_atomic_store((unsigned short*)p, x.u, __ATOMIC_RELAXED,
                     __HIP_MEMORY_SCOPE_AGENT);
}
DI bf16x8 mk8(u64 lo, u64 hi) {
  u64x2 t; t[0] = lo; t[1] = hi;
  return __builtin_bit_cast(bf16x8, t);
}
DI f32x4 cload_f32x4(const float* p) {
  union { u64 u[2]; f32x4 v; } x;
  x.u[0] = cload_u64(p); x.u[1] = cload_u64(p + 2);
  return x.v;
}
DI void cstore_f32x4(float* p, f32x4 v) {
  union { f32x4 v; u64 u[2]; } x; x.v = v;
  cstore_u64(p, x.u[0]); cstore_u64(p + 2, x.u[1]);
}

// ---------------------------------------------------------------------------
// LDS chunk layout: [rows][64 k] bf16 = 128 B/row, slot s (16B) holds
// act[r][k0 + (s ^ (r&7))*8]  (XOR swizzle -> bank-balanced ds_read_b128).
// T14 split staging: issue coherent loads -> (caller runs MFMAs) -> ds_write.
// ---------------------------------------------------------------------------
template<int SE>
DI void sload128(u64* v, const bf16* act, int k0, int wave, int lane)
{
  const int rsub = lane >> 3, sx = lane & 7;
#pragma unroll
  for (int j = 0; j < 4; ++j) {
    const int r = (wave * 4 + j) * 8 + rsub;
    const bf16* g = act + (long)r * SE + k0 + ((sx ^ (r & 7)) << 3);
    v[2 * j]     = cload_u64(g);
    v[2 * j + 1] = cload_u64(g + 4);
  }
}
DI void swrite128(const u64* v, char* ldsb, int wave, int lane)
{
#pragma unroll
  for (int j = 0; j < 4; ++j) {
    u64x2 t; t[0] = v[2 * j]; t[1] = v[2 * j + 1];
    *(u64x2*)(ldsb + (wave * 4 + j) * 1024 + lane * 16) = t;
  }
}
template<int SE>
DI void sload64x2(u64* v, const bf16* a1, const bf16* a2, int k0,
                  int wave, int lane)
{
  const int rsub = lane >> 3, sx = lane & 7;
#pragma unroll
  for (int j = 0; j < 2; ++j) {
    const int r = (wave * 2 + j) * 8 + rsub;
    const long go = (long)r * SE + k0 + ((sx ^ (r & 7)) << 3);
    v[4 * j]     = cload_u64(a1 + go);
    v[4 * j + 1] = cload_u64(a1 + go + 4);
    v[4 * j + 2] = cload_u64(a2 + go);
    v[4 * j + 3] = cload_u64(a2 + go + 4);
  }
}
DI void swrite64x2(const u64* v, char* ldsb, int wave, int lane)
{
#pragma unroll
  for (int j = 0; j < 2; ++j) {
    u64x2 ta, tb;
    ta[0] = v[4 * j];     ta[1] = v[4 * j + 1];
    tb[0] = v[4 * j + 2]; tb[1] = v[4 * j + 3];
    *(u64x2*)(ldsb + (wave * 2 + j) * 1024 + lane * 16) = ta;
    *(u64x2*)(ldsb + 8192 + (wave * 2 + j) * 1024 + lane * 16) = tb;
  }
}

DI bf16x8 ldsAf(const char* p, int r, int m)   // m = k-slot index (pre-XOR)
{
  return *(const bf16x8*)(p + r * 128 + ((m ^ (r & 7)) << 4));
}

// --------------------------- LSTM level (device part) ----------------------
// task in [0,96): bx=ntile64(32) x axis(3). Full batch per wave (NB=8).
DI void d_lstm(int bid, int tid, char* smem,
               const bf16* __restrict__ A0, long a0ss,
               const bf16* __restrict__ A1,
               const bf16* __restrict__ W,
               const float* __restrict__ bias,
               const float* __restrict__ csR,
               float* __restrict__ csW,
               bf16* __restrict__ hOut)
{
  const int bx = bid & 31, ax = bid >> 5;
  const int lane = tid & 63, wave = tid >> 6;
  const int q = lane >> 4, col = lane & 15;
  const int n0 = bx * 64 + wave * 16;
  const bf16* wrow = W + (long)ax * 10485760L + (long)(n0 + col) * 1024;
  const bf16* a0 = A0 + (long)ax * a0ss;
  const bf16* a1 = A1 + (long)ax * 65536;
  f32x4 acc[8] = {};
  u64 v[8];
  sload128<512>(v, a0, 0, wave, lane);
  swrite128(v, smem, wave, lane);
  __syncthreads();
#pragma unroll 2
  for (int c = 0; c < 16; ++c) {
    if (c < 15) {
      const bf16* an = ((c + 1) < 8) ? a0 : a1;
      sload128<512>(v, an, ((c + 1) & 7) * 64, wave, lane);
    }
    const char* p = smem + ((c & 1) << 14);
#pragma unroll
    for (int ki = 0; ki < 2; ++ki) {
      bf16x8 wf = *(const bf16x8*)(wrow + c * 64 + ki * 32 + q * 8);
#pragma unroll
      for (int bt = 0; bt < 8; ++bt)
        acc[bt] = __builtin_amdgcn_mfma_f32_16x16x32_bf16(
            wf, ldsAf(p, bt * 16 + col, ki * 4 + q), acc[bt], 0, 0, 0);
    }
    if (c < 15) swrite128(v, smem + (((c + 1) & 1) << 14), wave, lane);
    __syncthreads();
  }
  const int o = (n0 >> 2) + q;
  const float* bi = bias + (long)ax * 10240;
  float b0f = bi[o], b1f = bi[512 + o], b2f = bi[1024 + o], b3f = bi[1536 + o];
  const float* csr = csR + (long)ax * 65536;
  float* csw = csW + (long)ax * 65536;
  bf16* hl = hOut + (long)ax * 65536;
#pragma unroll
  for (int bt = 0; bt < 8; ++bt) {
    int b = bt * 16 + col;
    float ig = sigmoidf_(acc[bt][0] + b0f);
    float fg = sigmoidf_(acc[bt][1] + b1f);
    float gg = tanhf_   (acc[bt][2] + b2f);
    float og = sigmoidf_(acc[bt][3] + b3f);
    long idx = (long)b * 512 + o;
    float cn = fg * cload_f32(csr + idx) + ig * gg;
    cstore_f32(csw + idx, cn);
    cstore_bf16(hl + idx, (bf16)(og * tanhf_(cn)));
  }
}

// --------------------------- cell_fn gates (device part) -------------------
// task in [0,480): bx=ntile64(32) x sl=l*3+a(15). Full batch per wave (NB=8).
DI void d_cell(int bid, int tid, char* smem,
               const bf16* __restrict__ hg, const bf16* __restrict__ hsC,
               const bf16* __restrict__ Wg, const float* __restrict__ bgp,
               const float* __restrict__ csC,
               bf16* __restrict__ icat, bf16* __restrict__ ccat)
{
  const int bx = bid & 31, sl = bid >> 5;
  const int l = sl / 3, a = sl - l * 3;
  const int lane = tid & 63, wave = tid >> 6;
  const int q = lane >> 4, col = lane & 15;
  const int n0 = bx * 64 + wave * 16;
  const bf16* wrow = Wg + (long)sl * 2097152L + (long)(n0 + col) * 1024;
  const bf16* a0 = hg;
  const bf16* a1 = hsC + (long)sl * 65536;
  f32x4 acc[8] = {};
  u64 v[8];
  sload128<512>(v, a0, 0, wave, lane);
  swrite128(v, smem, wave, lane);
  __syncthreads();
#pragma unroll 2
  for (int c = 0; c < 16; ++c) {
    if (c < 15) {
      const bf16* an = ((c + 1) < 8) ? a0 : a1;
      sload128<512>(v, an, ((c + 1) & 7) * 64, wave, lane);
    }
    const char* p = smem + ((c & 1) << 14);
#pragma unroll
    for (int ki = 0; ki < 2; ++ki) {
      bf16x8 wf = *(const bf16x8*)(wrow + c * 64 + ki * 32 + q * 8);
#pragma unroll
      for (int bt = 0; bt < 8; ++bt)
        acc[bt] = __builtin_amdgcn_mfma_f32_16x16x32_bf16(
            wf, ldsAf(p, bt * 16 + col, ki * 4 + q), acc[bt], 0, 0, 0);
    }
    if (c < 15) swrite128(v, smem + (((c + 1) & 1) << 14), wave, lane);
    __syncthreads();
  }
  const int z = (n0 >> 2) + q;
  const float* bgl = bgp + (long)sl * 1536;
  float g0 = bgl[z], g1 = bgl[512 + z], g2 = bgl[1024 + z];
  const float* csl = csC + (long)sl * 65536;
  const long obase = (long)l * 196608 + (long)a * 512 + z;
#pragma unroll
  for (int bt = 0; bt < 8; ++bt) {
    int b = bt * 16 + col;
    float ig = sigmoidf_(acc[bt][0] + g0);
    float fg = sigmoidf_(acc[bt][1] + g1);
    float gg = tanhf_   (acc[bt][2] + g2);
    float sc = cload_f32(csl + (long)b * 512 + z);
    float icl = ig * sc;
    float ccl = fg * gg + icl;
    long oi = obase + (long)b * 1536;
    cstore_bf16(icat + oi, (bf16)icl);
    cstore_bf16(ccat + oi, (bf16)ccl);
  }
}

// ----------------------- t1/t2 dual GEMM (device part) ---------------------
// task in [0,80): bx=ntile64(8) x by=batch-half(2) x l(5). NB=4 dual.
DI void d_tg(int bid, int tid, char* smem,
             const bf16* __restrict__ icat, const bf16* __restrict__ ccat,
             const bf16* __restrict__ Wt, const float* __restrict__ bilc,
             float* __restrict__ t1s, float* __restrict__ t2s)
{
  const int bx = bid & 7, by = (bid >> 3) & 1, l = bid >> 4;
  const int lane = tid & 63, wave = tid >> 6;
  const int q = lane >> 4, col = lane & 15;
  const int n0 = bx * 64 + wave * 16;
  const int b0 = by * 64;
  const bf16* wrow = Wt + (long)l * 786432L + (long)(n0 + col) * 1536;
  const bf16* ic = icat + (long)l * 196608 + (long)b0 * 1536;
  const bf16* cc = ccat + (long)l * 196608 + (long)b0 * 1536;
  f32x4 a1[4] = {}, a2[4] = {};
  u64 v[8];
  sload64x2<1536>(v, ic, cc, 0, wave, lane);
  swrite64x2(v, smem, wave, lane);
  __syncthreads();
#pragma unroll 2
  for (int c = 0; c < 24; ++c) {
    if (c < 23) sload64x2<1536>(v, ic, cc, (c + 1) * 64, wave, lane);
    const char* p = smem + ((c & 1) << 14);
#pragma unroll
    for (int ki = 0; ki < 2; ++ki) {
      bf16x8 wf = *(const bf16x8*)(wrow + c * 64 + ki * 32 + q * 8);
#pragma unroll
      for (int bt = 0; bt < 4; ++bt) {
        int rl = bt * 16 + col;
        a1[bt] = __builtin_amdgcn_mfma_f32_16x16x32_bf16(
            wf, ldsAf(p, rl, ki * 4 + q), a1[bt], 0, 0, 0);
        a2[bt] = __builtin_amdgcn_mfma_f32_16x16x32_bf16(
            wf, ldsAf(p + 8192, rl, ki * 4 + q), a2[bt], 0, 0, 0);
      }
    }
    if (c < 23) swrite64x2(v, smem + (((c + 1) & 1) << 14), wave, lane);
    __syncthreads();
  }
  const int yb = n0 + 4 * q;
  const float* bl = bilc + (long)l * 1536;
  f32x4 bs;
#pragma unroll
  for (int r = 0; r < 4; ++r) bs[r] = bl[yb + r] + bl[512 + yb + r] + bl[1024 + yb + r];
#pragma unroll
  for (int bt = 0; bt < 4; ++bt) {
    int b = b0 + bt * 16 + col;
    f32x4 v1 = a1[bt] + bs, v2 = a2[bt] + bs;
    cstore_f32x4(t1s + ((long)l * 128 + b) * 512 + yb, v1);
    cstore_f32x4(t2s + ((long)l * 128 + b) * 512 + yb, v2);
  }
}

// ------------------ softmax/sigmoid combine (device part) ------------------
// task in [0,160): bx=b-tile-of-4(32) x l(5); one (l,b)-row of 512 per wave.
DI void d_comb(int bid, int tid,
               const float* __restrict__ t1s, const float* __restrict__ t2s,
               bf16* __restrict__ cat)
{
  const int bx = bid & 31, l = bid >> 5;
  const int lane = tid & 63, wave = tid >> 6;
  const int b = bx * 4 + wave;
  const float* r1 = t1s + ((long)l * 128 + b) * 512 + lane * 8;
  const float* r2 = t2s + ((long)l * 128 + b) * 512 + lane * 8;
  f32x4 u0 = cload_f32x4(r1), u1 = cload_f32x4(r1 + 4);
  float mx = u0[0];
#pragma unroll
  for (int j = 1; j < 4; ++j) mx = fmaxf(mx, u0[j]);
#pragma unroll
  for (int j = 0; j < 4; ++j) mx = fmaxf(mx, u1[j]);
  for (int d = 32; d > 0; d >>= 1) mx = fmaxf(mx, __shfl_xor(mx, d, 64));
  float e[8], ss = 0.f;
#pragma unroll
  for (int j = 0; j < 4; ++j) { e[j] = __expf(u0[j] - mx); ss += e[j]; }
#pragma unroll
  for (int j = 0; j < 4; ++j) { e[4 + j] = __expf(u1[j] - mx); ss += e[4 + j]; }
  for (int d = 32; d > 0; d >>= 1) ss += __shfl_xor(ss, d, 64);
  float inv = 1.0f / ss;
  f32x4 w0 = cload_f32x4(r2), w1 = cload_f32x4(r2 + 4);
  bf16x8 ob;
#pragma unroll
  for (int j = 0; j < 4; ++j) ob[j]     = (bf16)(sigmoidf_(w0[j]) * e[j]     * inv);
#pragma unroll
  for (int j = 0; j < 4; ++j) ob[4 + j] = (bf16)(sigmoidf_(w1[j]) * e[4 + j] * inv);
  union { bf16x8 b; u64 u[2]; } ox; ox.b = ob;
  bf16* cp = cat + (long)b * 2560 + l * 512 + lane * 8;
  cstore_u64(cp, ox.u[0]);
  cstore_u64(cp + 4, ox.u[1]);
}

// ---------------- single_li split-K GEMM (device part) ---------------------
// task in [0,128): bx=ntile64(8) x by=batch-quarter(4) x kc(4). NB=2, K=640.
DI void d_slg(int bid, int tid,
              const bf16* __restrict__ cat, const bf16* __restrict__ Wsl,
              float* __restrict__ hnewp)
{
  const int bx = bid & 7, by = (bid >> 3) & 3, kc = bid >> 5;
  const int lane = tid & 63, wave = tid >> 6;
  const int q = lane >> 4, col = lane & 15;
  const int n0 = bx * 64 + wave * 16;
  const int b0 = by * 32;
  const bf16* wrow = Wsl + (long)(n0 + col) * 2560 + kc * 640;
  const bf16* act = cat + kc * 640 + (long)b0 * 2560;
  f32x4 acc[2] = {};
#pragma unroll
  for (int ki = 0; ki < 20; ++ki) {
    const int k = ki * 32 + q * 8;
    bf16x8 wf = *(const bf16x8*)(wrow + k);
#pragma unroll
    for (int bt = 0; bt < 2; ++bt) {
      const bf16* ap = act + (long)(bt * 16 + col) * 2560 + k;
      bf16x8 af = mk8(cload_u64(ap), cload_u64(ap + 4));
      acc[bt] = __builtin_amdgcn_mfma_f32_16x16x32_bf16(wf, af, acc[bt], 0, 0, 0);
    }
  }
  const int nb = n0 + 4 * q;
#pragma unroll
  for (int bt = 0; bt < 2; ++bt) {
    int b = b0 + bt * 16 + col;
    cstore_f32x4(hnewp + ((long)kc * 128 + b) * 512 + nb, acc[bt]);
  }
}

// -------- finalize: sum K-partials, +bsl, write h_g (bf16) and y ----------
// task in [0,32): one wave per batch row b.
DI void d_fin(int bid, int tid,
              const float* __restrict__ hnewp, const float* __restrict__ bsl,
              const float* __restrict__ wlin, const float* __restrict__ blin,
              bf16* __restrict__ hg, float* __restrict__ out, int t)
{
  const int lane = tid & 63, wave = tid >> 6;
  const int b = bid * 4 + wave;
  const int h0 = lane * 8;
  f32x4 s0 = {0,0,0,0}, s1 = {0,0,0,0};
#pragma unroll
  for (int kc = 0; kc < 4; ++kc) {
    const float* p = hnewp + ((long)kc * 128 + b) * 512 + h0;
    s0 += cload_f32x4(p);
    s1 += cload_f32x4(p + 4);
  }
  s0 += *(const f32x4*)(bsl + h0);
  s1 += *(const f32x4*)(bsl + h0 + 4);
  bf16x8 hb;
#pragma unroll
  for (int j = 0; j < 4; ++j) { hb[j] = (bf16)s0[j]; hb[4 + j] = (bf16)s1[j]; }
  union { bf16x8 b; u64 u[2]; } hx; hx.b = hb;
  bf16* hp = hg + (long)b * 512 + h0;
  cstore_u64(hp, hx.u[0]);
  cstore_u64(hp + 4, hx.u[1]);
  const float* wl = wlin + (long)t * 512 + h0;
  f32x4 w0 = *(const f32x4*)wl, w1 = *(const f32x4*)(wl + 4);
  float dot = s0[0]*w0[0] + s0[1]*w0[1] + s0[2]*w0[2] + s0[3]*w0[3]
            + s1[0]*w1[0] + s1[1]*w1[1] + s1[2]*w1[2] + s1[3]*w1[3];
  for (int d = 32; d > 0; d >>= 1) dot += __shfl_xor(dot, d, 64);
  if (lane == 0) out[t * 128 + b] = dot + blin[t];
}

// ------------------------- grid barrier (persistent) -----------------------
// Contention-free flag barrier. Arrival + go are fetch_max RMWs: RMWs go to
// the cross-XCD coherent point (round-2-proven visible to relaxed polls).
// Release-only agent fence (s_waitcnt + buffer_wbl2, NO buffer_inv) writes
// back this XCD's dirty lines without evicting clean weight lines — the
// acquire-side invalidate was round-2's 2.5x regression. Consumers read
// cross-block data only via coherent (sc-bit) loads, so no acquire fence.
// Flags monotonic (round never resets) -> no reuse race; ">=" polls.
#define NBLK 512
DI void gsync(unsigned* bar, int bid, unsigned round)
{
  __syncthreads();   // drains vmcnt/lgkmcnt for ALL threads of the block
  if (threadIdx.x == 0) {
    __builtin_amdgcn_fence(__ATOMIC_RELEASE, "agent");
    __hip_atomic_fetch_max(&bar[bid], round, __ATOMIC_RELAXED,
                           __HIP_MEMORY_SCOPE_AGENT);
  }
  if (bid == 0) {
    for (int i = threadIdx.x; i < NBLK; i += 256)
      while (__hip_atomic_load(&bar[i], __ATOMIC_RELAXED,
                               __HIP_MEMORY_SCOPE_AGENT) < round)
        __builtin_amdgcn_s_sleep(1);
    __syncthreads();
    if (threadIdx.x == 0)
      __hip_atomic_fetch_max(&bar[600], round, __ATOMIC_RELAXED,
                             __HIP_MEMORY_SCOPE_AGENT);
  } else if (threadIdx.x == 0) {
    while (__hip_atomic_load(&bar[600], __ATOMIC_RELAXED,
                             __HIP_MEMORY_SCOPE_AGENT) < round)
      __builtin_amdgcn_s_sleep(1);
  }
  __syncthreads();
}

// ---------------------- persistent full-sequence kernel --------------------
struct KArgs {
  const bf16 *xbf, *Wcat, *Wg, *Wt, *Wslb;
  const float *b_l, *bg, *bilc, *bsl, *Wlin, *blin;
  bf16 *hs0, *hs1, *hgb, *icat, *ccat, *catb;
  float *cs0, *cs1, *t1s, *t2s, *hnp, *out;
  unsigned *bar;
};

// Grid = 512 blocks x 256 threads @ launch_bounds(256,2) = 2 blocks/CU —
// the config round-2 PROVED co-resident (OccupancyPercent 24.9%, VGPR 100).
// Phase 0 has 576 tasks: blocks 448..511 take a second cell task (1023-bid).
__global__ __launch_bounds__(256, 2) void k_main(KArgs A)
{
  __shared__ __align__(16) char smem[32768];
  const int bid = blockIdx.x;
  const int tid = threadIdx.x;
  unsigned round = 0;

  for (int s = 0; s < 65; ++s) {
    const int t  = (s < 64) ? s : 63;     // lstm step (active iff s<64)
    const int tc = s - 1;                 // chain step (active iff s>0)
    const bool ls = (s < 64), cs_ = (s > 0);
    const bf16*  hsR = (t & 1) ? A.hs1 : A.hs0;
    bf16*        hsW = (t & 1) ? A.hs0 : A.hs1;
    const float* csR = (t & 1) ? A.cs1 : A.cs0;
    float*       csW = (t & 1) ? A.cs0 : A.cs1;
    const bf16*  hsC = (tc & 1) ? A.hs0 : A.hs1;   // = hsW(tc)
    const float* csC = (tc & 1) ? A.cs0 : A.cs1;   // = csW(tc)

#define LSTM_L(l, task) d_lstm(task, tid, smem, \
      ((l) == 0 ? A.xbf + (long)t * 65536 : (const bf16*)(hsW + (long)((l)-1) * 196608)), \
      ((l) == 0 ? 0L : 65536L), \
      hsR + (long)(l) * 196608, A.Wcat + (long)(l) * 2097152, \
      A.b_l + (long)(l) * 2048, csR + (long)(l) * 196608, \
      csW + (long)(l) * 196608, hsW + (long)(l) * 196608)

    // phase 0: lstm level0 (96) + cell gates (480); fixed task slots 0..575
    if (ls && bid < 96) LSTM_L(0, bid);
    else if (cs_ && bid >= 96)
      d_cell(bid - 96, tid, smem, A.hgb, hsC, A.Wg, A.bg, csC, A.icat, A.ccat);
    {
      const int t2 = 1023 - bid;          // blocks 448..511 -> slots 512..575
      if (cs_ && t2 >= 512 && t2 < 576)
        d_cell(t2 - 96, tid, smem, A.hgb, hsC, A.Wg, A.bg, csC, A.icat, A.ccat);
    }
    gsync(A.bar, bid, ++round);

    // phase 1: lstm level1 (96) + t1/t2 dual GEMM (80)
    if (ls && bid < 96) LSTM_L(1, bid);
    else if (cs_ && bid >= 96 && bid < 176)
      d_tg(bid - 96, tid, smem, A.icat, A.ccat, A.Wt, A.bilc, A.t1s, A.t2s);
    gsync(A.bar, bid, ++round);

    // phase 2: lstm level2 (96) + combine (160)
    if (ls && bid < 96) LSTM_L(2, bid);
    else if (cs_ && bid >= 96 && bid < 256)
      d_comb(bid - 96, tid, A.t1s, A.t2s, A.catb);
    gsync(A.bar, bid, ++round);

    // phase 3: lstm level3 (96) + single_li split-K (128)
    if (ls && bid < 96) LSTM_L(3, bid);
    else if (cs_ && bid >= 96 && bid < 224)
      d_slg(bid - 96, tid, A.catb, A.Wslb, A.hnp);
    gsync(A.bar, bid, ++round);

    // phase 4: lstm level4 (96) + finalize (32)
    if (ls && bid < 96) LSTM_L(4, bid);
    else if (cs_ && bid >= 96 && bid < 128)
      d_fin(bid - 96, tid, A.hnp, A.bsl, A.Wlin, A.blin, A.hgb, A.out, tc);
    gsync(A.bar, bid, ++round);
#undef LSTM_L
  }
}

// ------------------------- weight conversion kernels -----------------------
__global__ __launch_bounds__(256) void cvt_wxh(const float* __restrict__ Wx,
    const float* __restrict__ Wh, bf16* __restrict__ dst)
{
  long idx = ((long)blockIdx.x * 256 + threadIdx.x) * 4;   // [al][n][k], n=4o+g
  int k = (int)(idx & 1023);
  int n = (int)((idx >> 10) & 2047);
  long al = idx >> 21;                                     // a*5+l
  int g = n & 3, o = n >> 2;
  const float* src = (k < 512)
      ? Wx + ((al * 4 + g) * 512 + o) * 512 + k
      : Wh + ((al * 4 + g) * 512 + o) * 512 + (k - 512);
  f32x4 v = *(const f32x4*)src;
  bf16x4 ov;
#pragma unroll
  for (int j = 0; j < 4; ++j) ov[j] = (bf16)v[j];
  *(bf16x4*)(dst + idx) = ov;
}

__global__ __launch_bounds__(256) void cvt_wg(const float* __restrict__ Wg_h,
    const float* __restrict__ Wg_p, bf16* __restrict__ dst)
{
  long idx = ((long)blockIdx.x * 256 + threadIdx.x) * 4;   // [la][n=4z+g][k], g==3 pad
  int k = (int)(idx & 1023);
  int n = (int)((idx >> 10) & 2047);
  long la = idx >> 21;                                     // l*3+a
  int g = n & 3, z = n >> 2;
  f32x4 v = {0, 0, 0, 0};
  if (g < 3) {
    const float* src = (k < 512)
        ? Wg_h + ((la * 3 + g) * 512 + z) * 512 + k
        : Wg_p + ((la * 3 + g) * 512 + z) * 512 + (k - 512);
    v = *(const f32x4*)src;
  }
  bf16x4 ov;
#pragma unroll
  for (int j = 0; j < 4; ++j) ov[j] = (bf16)v[j];
  *(bf16x4*)(dst + idx) = ov;
}

__global__ __launch_bounds__(256) void cvt_wt(const float* __restrict__ Wilc,
                                              bf16* __restrict__ dst)
{
  long idx = (long)blockIdx.x * 256 + threadIdx.x;         // [l][y][k=a*512+z]
  int k = (int)(idx % 1536);
  long rest = idx / 1536;
  int y = (int)(rest & 511);
  int l = (int)(rest >> 9);
  int a = k >> 9, z = k & 511;
  dst[idx] = (bf16)Wilc[(((long)l * 3 + a) * 512 + z) * 512 + y];
}

__global__ __launch_bounds__(256) void k_cast(const float* __restrict__ s,
                                              bf16* __restrict__ d)
{
  long i = ((long)blockIdx.x * 256 + threadIdx.x) * 4;
  f32x4 v = *(const f32x4*)(s + i);
  bf16x4 ov;
#pragma unroll
  for (int j = 0; j < 4; ++j) ov[j] = (bf16)v[j];
  *(bf16x4*)(d + i) = ov;
}

__global__ __launch_bounds__(256) void k_zero(uint4* __restrict__ p, long n)
{
  long i = (long)blockIdx.x * 256 + threadIdx.x;
  if (i < n) p[i] = make_uint4(0, 0, 0, 0);
}

// ---------------------------------------------------------------------------
extern "C" void kernel_launch(void* const* d_in, const int* in_sizes, int n_in,
                              void* d_out, int out_size, void* d_ws, size_t ws_size,
                              hipStream_t stream)
{
  const float* x    = (const float*)d_in[0];
  const float* Wx   = (const float*)d_in[1];
  const float* Wh   = (const float*)d_in[2];
  const float* b_l  = (const float*)d_in[3];
  const float* Wg_h = (const float*)d_in[4];
  const float* Wg_p = (const float*)d_in[5];
  const float* bg   = (const float*)d_in[6];
  const float* Wilc = (const float*)d_in[7];
  const float* bilc = (const float*)d_in[8];
  const float* Wsl  = (const float*)d_in[9];
  const float* bsl  = (const float*)d_in[10];
  const float* Wlin = (const float*)d_in[11];
  const float* blin = (const float*)d_in[12];
  float* out = (float*)d_out;

  char* w = (char*)d_ws;
  auto alloc = [&](long bytes) { char* p = w; w += (bytes + 255) & ~255L; return p; };
  bf16* Wcat = (bf16*)alloc(31457280L * 2);   // [a][l][2048][1024]
  bf16* Wg   = (bf16*)alloc(31457280L * 2);   // [l*3+a][2048][1024]
  bf16* Wt   = (bf16*)alloc(3932160L * 2);    // [l][512][1536]
  bf16* Wslb = (bf16*)alloc(1310720L * 2);    // [512][2560]
  bf16* xbf  = (bf16*)alloc(4194304L * 2);    // [t][b][512]
  char* zbase = w;
  bf16* hs0  = (bf16*)alloc(983040L * 2);     // [l][a][b][512] ping
  bf16* hs1  = (bf16*)alloc(983040L * 2);     // pong
  bf16* hgb  = (bf16*)alloc(65536L * 2);      // [b][512]
  float* cs0 = (float*)alloc(983040L * 4);    // [l][a][b][512] ping
  float* cs1 = (float*)alloc(983040L * 4);    // pong
  unsigned* bar = (unsigned*)alloc(4096);     // flag barrier (zeroed)
  long zbytes = w - zbase;
  bf16* icat = (bf16*)alloc(983040L * 2);     // [l][b][1536]
  bf16* ccat = (bf16*)alloc(983040L * 2);
  float* t1s = (float*)alloc(327680L * 4);    // [l][b][512]
  float* t2s = (float*)alloc(327680L * 4);
  bf16* catb = (bf16*)alloc(327680L * 2);     // [b][2560]
  float* hnp = (float*)alloc(262144L * 4);    // [kc][b][512]
  (void)ws_size; (void)n_in; (void)in_sizes; (void)out_size;

  // --- setup (runs every call; ws is re-poisoned by the harness) ---
  cvt_wxh<<<30720, 256, 0, stream>>>(Wx, Wh, Wcat);
  cvt_wg <<<30720, 256, 0, stream>>>(Wg_h, Wg_p, Wg);
  cvt_wt <<<15360, 256, 0, stream>>>(Wilc, Wt);
  k_cast <<<1280,  256, 0, stream>>>(Wsl, Wslb);
  k_cast <<<4096,  256, 0, stream>>>(x, xbf);
  {
    long n16 = zbytes / 16;
    k_zero<<<(int)((n16 + 255) / 256), 256, 0, stream>>>((uint4*)zbase, n16);
  }

  // --- single persistent kernel runs the whole pipelined sequence ----------
  KArgs A;
  A.xbf = xbf; A.Wcat = Wcat; A.Wg = Wg; A.Wt = Wt; A.Wslb = Wslb;
  A.b_l = b_l; A.bg = bg; A.bilc = bilc; A.bsl = bsl; A.Wlin = Wlin; A.blin = blin;
  A.hs0 = hs0; A.hs1 = hs1; A.hgb = hgb; A.icat = icat; A.ccat = ccat; A.catb = catb;
  A.cs0 = cs0; A.cs1 = cs1; A.t1s = t1s; A.t2s = t2s; A.hnp = hnp; A.out = out;
  A.bar = bar;
  k_main<<<512, 256, 0, stream>>>(A);
}